// Round 17
// baseline (65.184 us; speedup 1.0000x reference)
//
#include <hip/hip_runtime.h>
#include <cstdint>
#include <cstddef>

#define NB 8
#define NG 64
#define NP 50000
#define NBLK 98                  // ceil((NP/2)/256) streaming blocks per batch
#define NSTREAM (NBLK * NB)      // 784 streaming blocks
#define NPCH 32                  // argmax p-chunks per row
#define PCH 1563                 // ceil(NP/NPCH); 32*1563 = 50016 >= NP
#define NAMAX (NPCH * (NG / 8) * NB)  // 2048 argmax blocks
#define NTOT (NSTREAM + NAMAX)   // 2832

__device__ __forceinline__ void opaque(float& x) { asm volatile("" : "+v"(x)); }
__device__ __forceinline__ unsigned long long umax64(unsigned long long a, unsigned long long b) {
    return a > b ? a : b;
}

// ---------------------------------------------------------------------------
// Fat kernel, MONOTONIC role dispatch (R12-proven, 55.0 µs), with one change:
// pos_mask is pre-zeroed by hipMemsetAsync at fill rate (6.9 TB/s), and the
// streaming role stores 1.0f ONLY where iou > 0.7 (exec-masked scalar store,
// ~0 bytes for typical waves) — cutting ~100 MB of dense in-kernel stores.
template<bool WITH_ARGMAX>
__global__ __launch_bounds__(256) void fused_main(
    const float* __restrict__ pred,
    const float* __restrict__ gt,
    float* __restrict__ out_iou,
    float* __restrict__ out_pos,
    float* __restrict__ out_neg,
    unsigned long long* __restrict__ part)
{
    const int bid = blockIdx.x;
    const int tid = threadIdx.x;

    if (!WITH_ARGMAX || bid < NSTREAM) {
        // ----------------- streaming role (R3 body, sparse pos) -----------------
        __shared__ float s_gx0[NG], s_gy0[NG], s_gx1[NG], s_gy1[NG], s_ga[NG];
        const int b  = bid / NBLK;
        const int bx = bid % NBLK;

        if (tid < NG) {
            const float4 gb = reinterpret_cast<const float4*>(gt)[b * NG + tid];
            float hw = 0.5f * gb.z, hh = 0.5f * gb.w;   // exact, FMA-safe
            float x0 = gb.x - hw, y0 = gb.y - hh;
            float x1 = gb.x + hw, y1 = gb.y + hh;
            float ga = (x1 - x0) * (y1 - y0);
            opaque(ga);                                  // block FMA contraction
            s_gx0[tid] = x0; s_gy0[tid] = y0;
            s_gx1[tid] = x1; s_gy1[tid] = y1;
            s_ga[tid]  = ga;
        }
        __syncthreads();

        const int p = 2 * (bx * 256 + tid);
        if (p >= NP) return;                             // no barriers after this

        const float4 pb0 = reinterpret_cast<const float4*>(pred)[(size_t)b * NP + p];
        const float4 pb1 = reinterpret_cast<const float4*>(pred)[(size_t)b * NP + p + 1];

        float hw0 = 0.5f * pb0.z, hh0 = 0.5f * pb0.w;
        const float ax0 = pb0.x - hw0, ay0 = pb0.y - hh0;
        const float ax1 = pb0.x + hw0, ay1 = pb0.y + hh0;
        float pa0 = (ax1 - ax0) * (ay1 - ay0);
        opaque(pa0);

        float hw1 = 0.5f * pb1.z, hh1 = 0.5f * pb1.w;
        const float bx0 = pb1.x - hw1, by0 = pb1.y - hh1;
        const float bx1 = pb1.x + hw1, by1 = pb1.y + hh1;
        float pa1 = (bx1 - bx0) * (by1 - by0);
        opaque(pa1);

        float maxv0 = 0.0f, maxv1 = 0.0f;
        const size_t base = (size_t)b * NG * NP + (size_t)p;

        #pragma unroll 8
        for (int g = 0; g < NG; ++g) {
            const float gx0 = s_gx0[g], gy0 = s_gy0[g];
            const float gx1 = s_gx1[g], gy1 = s_gy1[g];
            const float ga  = s_ga[g];

            float w0 = fmaxf(fminf(gx1, ax1) - fmaxf(gx0, ax0), 0.0f);
            float h0 = fmaxf(fminf(gy1, ay1) - fmaxf(gy0, ay0), 0.0f);
            float inter0 = w0 * h0;
            opaque(inter0);                              // numpy op order: (ga+pa)-inter
            float iou0 = inter0 / ((ga + pa0) - inter0); // IEEE div

            float w1 = fmaxf(fminf(gx1, bx1) - fmaxf(gx0, bx0), 0.0f);
            float h1 = fmaxf(fminf(gy1, by1) - fmaxf(gy0, by0), 0.0f);
            float inter1 = w1 * h1;
            opaque(inter1);
            float iou1 = inter1 / ((ga + pa1) - inter1);

            float2 vi; vi.x = iou0; vi.y = iou1;
            *reinterpret_cast<float2*>(out_iou + base + (size_t)g * NP) = vi;

            // sparse pos: background is memset-0; store only the rare 1.0s
            if (iou0 > 0.7f) out_pos[base + (size_t)g * NP]     = 1.0f;
            if (iou1 > 0.7f) out_pos[base + (size_t)g * NP + 1] = 1.0f;

            maxv0 = fmaxf(maxv0, iou0);
            maxv1 = fmaxf(maxv1, iou1);
        }

        float2 vn; vn.x = (maxv0 < 0.3f) ? 1.0f : 0.0f;
                   vn.y = (maxv1 < 0.3f) ? 1.0f : 0.0f;
        *reinterpret_cast<float2*>(out_neg + (size_t)b * NP + p) = vn;
    } else {
        // ----------------- argmax role (R12-proven) -----------------
        __shared__ float a_gx0[8], a_gy0[8], a_gx1[8], a_gy1[8], a_ga[8];
        __shared__ unsigned long long s_part[8][4];

        const int a     = bid - NSTREAM;                 // 0..NAMAX-1
        const int chunk = a % NPCH;
        const int t2    = a / NPCH;
        const int gg    = t2 % (NG / 8);
        const int b     = t2 / (NG / 8);
        const int p0    = chunk * PCH;

        if (tid < 8) {
            const float4 gb = reinterpret_cast<const float4*>(gt)[b * NG + gg * 8 + tid];
            float hw = 0.5f * gb.z, hh = 0.5f * gb.w;
            float x0 = gb.x - hw, y0 = gb.y - hh;
            float x1 = gb.x + hw, y1 = gb.y + hh;
            float ga = (x1 - x0) * (y1 - y0);
            opaque(ga);
            a_gx0[tid] = x0; a_gy0[tid] = y0;
            a_gx1[tid] = x1; a_gy1[tid] = y1;
            a_ga[tid]  = ga;
        }
        __syncthreads();

        float        bv[8] = {-1.f,-1.f,-1.f,-1.f,-1.f,-1.f,-1.f,-1.f};
        unsigned int bp[8] = {0,0,0,0,0,0,0,0};

        for (int i = tid; i < PCH; i += 256) {
            const int p = p0 + i;
            if (p >= NP) break;
            const float4 pb = reinterpret_cast<const float4*>(pred)[(size_t)b * NP + p];
            float hw = 0.5f * pb.z, hh = 0.5f * pb.w;
            const float px0 = pb.x - hw, py0 = pb.y - hh;
            const float px1 = pb.x + hw, py1 = pb.y + hh;
            float pa = (px1 - px0) * (py1 - py0);
            opaque(pa);

            #pragma unroll
            for (int j = 0; j < 8; ++j) {
                // identical expression structure to streaming role -> bitwise-equal iou
                float w = fmaxf(fminf(a_gx1[j], px1) - fmaxf(a_gx0[j], px0), 0.0f);
                float h = fmaxf(fminf(a_gy1[j], py1) - fmaxf(a_gy0[j], py0), 0.0f);
                float inter = w * h;
                opaque(inter);                           // numpy op order: (ga+pa)-inter
                float iou = inter / ((a_ga[j] + pa) - inter);  // IEEE div
                if (iou > bv[j]) { bv[j] = iou; bp[j] = (unsigned int)p; }  // static idx
            }
        }

        const int lane = tid & 63;
        const int wv = tid >> 6;
        #pragma unroll
        for (int j = 0; j < 8; ++j) {
            unsigned long long k = 0;
            if (bv[j] >= 0.0f)
                k = ((unsigned long long)__float_as_uint(bv[j]) << 32) |
                    (unsigned long long)(0xFFFFFFFFu - bp[j]);
            #pragma unroll
            for (int s = 1; s < 64; s <<= 1)
                k = umax64(k, __shfl_xor(k, s, 64));
            if (lane == 0) s_part[j][wv] = k;
        }
        __syncthreads();

        if (tid < 8) {
            unsigned long long r = umax64(umax64(s_part[tid][0], s_part[tid][1]),
                                          umax64(s_part[tid][2], s_part[tid][3]));
            part[((size_t)b * NG + (size_t)(gg * 8 + tid)) * NPCH + chunk] = r;
        }
    }
}

// Reduce each row's NPCH partials, store 1.0 at the argmax position. 512 rows.
__global__ __launch_bounds__(256) void pos_fix(
    const unsigned long long* __restrict__ part,
    float* __restrict__ out_pos)
{
    const int row = blockIdx.x * 256 + threadIdx.x;    // b*NG + g
    if (row >= NB * NG) return;
    const unsigned long long* pr = part + (size_t)row * NPCH;
    unsigned long long r = pr[0];
    #pragma unroll
    for (int c = 1; c < NPCH; ++c) r = umax64(r, pr[c]);
    unsigned int idx = 0xFFFFFFFFu - (unsigned int)(r & 0xFFFFFFFFull);
    if (idx < NP) out_pos[(size_t)row * NP + idx] = 1.0f;
}

// Fallback (ws too small): dense pos path + re-scan argmax (no memset dependency).
__global__ __launch_bounds__(256) void stream2_full(
    const float* __restrict__ pred,
    const float* __restrict__ gt,
    float* __restrict__ out_iou,
    float* __restrict__ out_pos,
    float* __restrict__ out_neg)
{
    __shared__ float s_gx0[NG], s_gy0[NG], s_gx1[NG], s_gy1[NG], s_ga[NG];
    const int b = blockIdx.y;
    const int tid = threadIdx.x;
    if (tid < NG) {
        const float4 gb = reinterpret_cast<const float4*>(gt)[b * NG + tid];
        float hw = 0.5f * gb.z, hh = 0.5f * gb.w;
        float x0 = gb.x - hw, y0 = gb.y - hh;
        float x1 = gb.x + hw, y1 = gb.y + hh;
        float ga = (x1 - x0) * (y1 - y0);
        opaque(ga);
        s_gx0[tid] = x0; s_gy0[tid] = y0;
        s_gx1[tid] = x1; s_gy1[tid] = y1;
        s_ga[tid]  = ga;
    }
    __syncthreads();
    const int p = 2 * (blockIdx.x * 256 + tid);
    if (p >= NP) return;
    const float4 pb0 = reinterpret_cast<const float4*>(pred)[(size_t)b * NP + p];
    const float4 pb1 = reinterpret_cast<const float4*>(pred)[(size_t)b * NP + p + 1];
    float hw0 = 0.5f * pb0.z, hh0 = 0.5f * pb0.w;
    const float ax0 = pb0.x - hw0, ay0 = pb0.y - hh0;
    const float ax1 = pb0.x + hw0, ay1 = pb0.y + hh0;
    float pa0 = (ax1 - ax0) * (ay1 - ay0); opaque(pa0);
    float hw1 = 0.5f * pb1.z, hh1 = 0.5f * pb1.w;
    const float bx0 = pb1.x - hw1, by0 = pb1.y - hh1;
    const float bx1 = pb1.x + hw1, by1 = pb1.y + hh1;
    float pa1 = (bx1 - bx0) * (by1 - by0); opaque(pa1);
    float maxv0 = 0.0f, maxv1 = 0.0f;
    const size_t base = (size_t)b * NG * NP + (size_t)p;
    #pragma unroll 8
    for (int g = 0; g < NG; ++g) {
        const float gx0 = s_gx0[g], gy0 = s_gy0[g];
        const float gx1 = s_gx1[g], gy1 = s_gy1[g];
        const float ga  = s_ga[g];
        float w0 = fmaxf(fminf(gx1, ax1) - fmaxf(gx0, ax0), 0.0f);
        float h0 = fmaxf(fminf(gy1, ay1) - fmaxf(gy0, ay0), 0.0f);
        float inter0 = w0 * h0; opaque(inter0);
        float iou0 = inter0 / ((ga + pa0) - inter0);
        float w1 = fmaxf(fminf(gx1, bx1) - fmaxf(gx0, bx0), 0.0f);
        float h1 = fmaxf(fminf(gy1, by1) - fmaxf(gy0, by0), 0.0f);
        float inter1 = w1 * h1; opaque(inter1);
        float iou1 = inter1 / ((ga + pa1) - inter1);
        float2 vi; vi.x = iou0; vi.y = iou1;
        *reinterpret_cast<float2*>(out_iou + base + (size_t)g * NP) = vi;
        float2 vp; vp.x = (iou0 > 0.7f) ? 1.0f : 0.0f;
                   vp.y = (iou1 > 0.7f) ? 1.0f : 0.0f;
        *reinterpret_cast<float2*>(out_pos + base + (size_t)g * NP) = vp;
        maxv0 = fmaxf(maxv0, iou0);
        maxv1 = fmaxf(maxv1, iou1);
    }
    float2 vn; vn.x = (maxv0 < 0.3f) ? 1.0f : 0.0f;
               vn.y = (maxv1 < 0.3f) ? 1.0f : 0.0f;
    *reinterpret_cast<float2*>(out_neg + (size_t)b * NP + p) = vn;
}

__global__ __launch_bounds__(256) void argmax_scan(
    const float* __restrict__ out_iou,
    float* __restrict__ out_pos)
{
    const int row = blockIdx.x;
    const float4* r4 = reinterpret_cast<const float4*>(out_iou + (size_t)row * NP);
    float bv = -1.0f;
    int   bi = 0x7fffffff;
    for (int c = threadIdx.x; c < NP / 4; c += 256) {
        float4 v = r4[c];
        int p = 4 * c;
        if (v.x > bv) { bv = v.x; bi = p; }
        if (v.y > bv) { bv = v.y; bi = p + 1; }
        if (v.z > bv) { bv = v.z; bi = p + 2; }
        if (v.w > bv) { bv = v.w; bi = p + 3; }
    }
    #pragma unroll
    for (int s = 1; s < 64; s <<= 1) {
        float ov = __shfl_xor(bv, s, 64);
        int   oi = __shfl_xor(bi, s, 64);
        if (ov > bv || (ov == bv && oi < bi)) { bv = ov; bi = oi; }
    }
    __shared__ float sv[4];
    __shared__ int   si[4];
    const int wid = threadIdx.x >> 6;
    if ((threadIdx.x & 63) == 0) { sv[wid] = bv; si[wid] = bi; }
    __syncthreads();
    if (threadIdx.x == 0) {
        for (int w = 1; w < 4; ++w)
            if (sv[w] > bv || (sv[w] == bv && si[w] < bi)) { bv = sv[w]; bi = si[w]; }
        out_pos[(size_t)row * NP + bi] = 1.0f;
    }
}

extern "C" void kernel_launch(void* const* d_in, const int* in_sizes, int n_in,
                              void* d_out, int out_size, void* d_ws, size_t ws_size,
                              hipStream_t stream) {
    const float* pred = (const float*)d_in[0];
    const float* gt   = (const float*)d_in[1];
    float* out_iou = (float*)d_out;
    float* out_pos = out_iou + (size_t)NB * NG * NP;
    float* out_neg = out_pos + (size_t)NB * NG * NP;

    const size_t part_bytes = (size_t)NB * NG * NPCH * sizeof(unsigned long long); // 128 KB

    if (ws_size >= part_bytes) {
        unsigned long long* part = (unsigned long long*)d_ws;
        hipMemsetAsync(out_pos, 0, (size_t)NB * NG * NP * sizeof(float), stream);  // fill-rate zeroing
        fused_main<true><<<dim3(NTOT), dim3(256), 0, stream>>>(
            pred, gt, out_iou, out_pos, out_neg, part);
        pos_fix<<<dim3((NB * NG + 255) / 256), dim3(256), 0, stream>>>(part, out_pos);
    } else {
        fused_main<false><<<dim3(NSTREAM), dim3(256), 0, stream>>>(
            pred, gt, out_iou, out_pos, out_neg, nullptr);
        argmax_scan<<<dim3(NB * NG), dim3(256), 0, stream>>>(out_iou, out_pos);
    }
}

// Round 18
// 52.720 us; speedup vs baseline: 1.2364x; 1.2364x over previous
//
#include <hip/hip_runtime.h>
#include <cstdint>
#include <cstddef>

#define NB 8
#define NG 64
#define NP 50000
#define CH 2000                  // preds per chunk (25*2000 = NP exactly)
#define NCH 25                   // p-chunks
#define NGG 8                    // g-groups of 8
#define NNEG4 ((NB * NP / 4 + 255) / 256)  // 391 neg-combine blocks (float4)

__device__ __forceinline__ void opaque(float& x) { asm volatile("" : "+v"(x)); }
__device__ __forceinline__ unsigned long long umax64(unsigned long long a, unsigned long long b) {
    return a > b ? a : b;
}

// ---------------------------------------------------------------------------
// UNIFIED row-oriented kernel: computes each iou exactly ONCE.
// Block = (chunk, gg, b): 8 g-rows x 2000 preds. Writes iou+pos coalesced
// float2 along p; argmax rides free in bv[8]/bp[8] registers (one butterfly
// set per block); column-max goes to negpart for a cheap combine pass.
// (R12's fat kernel computed every iou twice — 10 us VALU tail. This doesn't.)
__global__ __launch_bounds__(256) void unified(
    const float* __restrict__ pred,
    const float* __restrict__ gt,
    float* __restrict__ out_iou,
    float* __restrict__ out_pos,
    float* __restrict__ negpart,
    unsigned long long* __restrict__ part)
{
    __shared__ float s_gx0[8], s_gy0[8], s_gx1[8], s_gy1[8], s_ga[8];
    const int b  = blockIdx.z;
    const int gg = blockIdx.y;
    const int p0 = blockIdx.x * CH;
    const int tid = threadIdx.x;

    if (tid < 8) {
        const float4 gb = reinterpret_cast<const float4*>(gt)[b * NG + gg * 8 + tid];
        float hw = 0.5f * gb.z, hh = 0.5f * gb.w;   // exact, FMA-safe
        float x0 = gb.x - hw, y0 = gb.y - hh;
        float x1 = gb.x + hw, y1 = gb.y + hh;
        float ga = (x1 - x0) * (y1 - y0);
        opaque(ga);
        s_gx0[tid] = x0; s_gy0[tid] = y0;
        s_gx1[tid] = x1; s_gy1[tid] = y1;
        s_ga[tid]  = ga;
    }
    __syncthreads();

    float        bv[8] = {-1.f,-1.f,-1.f,-1.f,-1.f,-1.f,-1.f,-1.f};
    unsigned int bp[8] = {0,0,0,0,0,0,0,0};

    #pragma unroll 1
    for (int idx = tid; idx < CH / 2; idx += 256) {   // 1000 pred-pairs
        const int p = p0 + 2 * idx;
        const float4 pb0 = reinterpret_cast<const float4*>(pred)[(size_t)b * NP + p];
        const float4 pb1 = reinterpret_cast<const float4*>(pred)[(size_t)b * NP + p + 1];

        float hw0 = 0.5f * pb0.z, hh0 = 0.5f * pb0.w;
        const float ax0 = pb0.x - hw0, ay0 = pb0.y - hh0;
        const float ax1 = pb0.x + hw0, ay1 = pb0.y + hh0;
        float pa0 = (ax1 - ax0) * (ay1 - ay0);
        opaque(pa0);

        float hw1 = 0.5f * pb1.z, hh1 = 0.5f * pb1.w;
        const float bx0 = pb1.x - hw1, by0 = pb1.y - hh1;
        const float bx1 = pb1.x + hw1, by1 = pb1.y + hh1;
        float pa1 = (bx1 - bx0) * (by1 - by0);
        opaque(pa1);

        float cmax0 = 0.0f, cmax1 = 0.0f;
        const size_t rbase = (size_t)b * NG * NP + (size_t)(gg * 8) * NP + (size_t)p;

        #pragma unroll
        for (int j = 0; j < 8; ++j) {
            const float gx0 = s_gx0[j], gy0 = s_gy0[j];
            const float gx1 = s_gx1[j], gy1 = s_gy1[j];
            const float ga  = s_ga[j];

            float w0 = fmaxf(fminf(gx1, ax1) - fmaxf(gx0, ax0), 0.0f);
            float h0 = fmaxf(fminf(gy1, ay1) - fmaxf(gy0, ay0), 0.0f);
            float inter0 = w0 * h0;
            opaque(inter0);                          // numpy op order: (ga+pa)-inter
            float iou0 = inter0 / ((ga + pa0) - inter0);  // IEEE div

            float w1 = fmaxf(fminf(gx1, bx1) - fmaxf(gx0, bx0), 0.0f);
            float h1 = fmaxf(fminf(gy1, by1) - fmaxf(gy0, by0), 0.0f);
            float inter1 = w1 * h1;
            opaque(inter1);
            float iou1 = inter1 / ((ga + pa1) - inter1);

            float2 vi; vi.x = iou0; vi.y = iou1;
            *reinterpret_cast<float2*>(out_iou + rbase + (size_t)j * NP) = vi;

            float2 vp; vp.x = (iou0 > 0.7f) ? 1.0f : 0.0f;
                       vp.y = (iou1 > 0.7f) ? 1.0f : 0.0f;
            *reinterpret_cast<float2*>(out_pos + rbase + (size_t)j * NP) = vp;

            cmax0 = fmaxf(cmax0, iou0);
            cmax1 = fmaxf(cmax1, iou1);

            // argmax accumulate: strict >, ascending p -> first occurrence
            if (iou0 > bv[j]) { bv[j] = iou0; bp[j] = (unsigned int)p; }
            if (iou1 > bv[j]) { bv[j] = iou1; bp[j] = (unsigned int)(p + 1); }
        }

        float2 mn; mn.x = cmax0; mn.y = cmax1;
        *reinterpret_cast<float2*>(negpart + ((size_t)b * NGG + gg) * NP + p) = mn;
    }

    // per-block argmax reduction: butterfly within wave, LDS across 4 waves
    __shared__ unsigned long long s_part[8][4];
    const int lane = tid & 63;
    const int wv = tid >> 6;
    #pragma unroll
    for (int j = 0; j < 8; ++j) {
        unsigned long long k = 0;
        if (bv[j] >= 0.0f)
            k = ((unsigned long long)__float_as_uint(bv[j]) << 32) |
                (unsigned long long)(0xFFFFFFFFu - bp[j]);
        #pragma unroll
        for (int s = 1; s < 64; s <<= 1)
            k = umax64(k, __shfl_xor(k, s, 64));
        if (lane == 0) s_part[j][wv] = k;
    }
    __syncthreads();

    if (tid < 8) {
        unsigned long long r = umax64(umax64(s_part[tid][0], s_part[tid][1]),
                                      umax64(s_part[tid][2], s_part[tid][3]));
        part[((size_t)b * NG + (size_t)(gg * 8 + tid)) * NCH + blockIdx.x] = r;
    }
}

// Combined fixup: blocks [0,NNEG4) merge 8 negpart slabs -> neg; last 2 blocks
// reduce 25 partial keys per row and set the argmax bit in pos.
__global__ __launch_bounds__(256) void fix_combined(
    const unsigned long long* __restrict__ part,
    const float* __restrict__ negpart,
    float* __restrict__ out_pos,
    float* __restrict__ out_neg)
{
    const int bid = blockIdx.x;
    const int tid = threadIdx.x;

    if (bid < NNEG4) {
        const int idx = bid * 256 + tid;             // float4 index over NB*NP/4
        if (idx < NB * (NP / 4)) {
            const int b = idx / (NP / 4);
            const int p = 4 * (idx % (NP / 4));
            float4 m = *reinterpret_cast<const float4*>(negpart + ((size_t)b * NGG + 0) * NP + p);
            #pragma unroll
            for (int gg = 1; gg < NGG; ++gg) {
                const float4 t = *reinterpret_cast<const float4*>(negpart + ((size_t)b * NGG + gg) * NP + p);
                m.x = fmaxf(m.x, t.x); m.y = fmaxf(m.y, t.y);
                m.z = fmaxf(m.z, t.z); m.w = fmaxf(m.w, t.w);
            }
            float4 vn;
            vn.x = (m.x < 0.3f) ? 1.0f : 0.0f;
            vn.y = (m.y < 0.3f) ? 1.0f : 0.0f;
            vn.z = (m.z < 0.3f) ? 1.0f : 0.0f;
            vn.w = (m.w < 0.3f) ? 1.0f : 0.0f;
            *reinterpret_cast<float4*>(out_neg + (size_t)b * NP + p) = vn;
        }
    } else {
        const int row = (bid - NNEG4) * 256 + tid;   // b*NG + g
        if (row < NB * NG) {
            const unsigned long long* pr = part + (size_t)row * NCH;
            unsigned long long r = pr[0];
            #pragma unroll
            for (int c = 1; c < NCH; ++c) r = umax64(r, pr[c]);
            unsigned int idx = 0xFFFFFFFFu - (unsigned int)(r & 0xFFFFFFFFull);
            if (idx < NP) out_pos[(size_t)row * NP + idx] = 1.0f;
        }
    }
}

// ------------------- fallback path (ws too small): R3-proven -------------------
__global__ __launch_bounds__(256) void stream2_full(
    const float* __restrict__ pred,
    const float* __restrict__ gt,
    float* __restrict__ out_iou,
    float* __restrict__ out_pos,
    float* __restrict__ out_neg)
{
    __shared__ float s_gx0[NG], s_gy0[NG], s_gx1[NG], s_gy1[NG], s_ga[NG];
    const int b = blockIdx.y;
    const int tid = threadIdx.x;
    if (tid < NG) {
        const float4 gb = reinterpret_cast<const float4*>(gt)[b * NG + tid];
        float hw = 0.5f * gb.z, hh = 0.5f * gb.w;
        float x0 = gb.x - hw, y0 = gb.y - hh;
        float x1 = gb.x + hw, y1 = gb.y + hh;
        float ga = (x1 - x0) * (y1 - y0);
        opaque(ga);
        s_gx0[tid] = x0; s_gy0[tid] = y0;
        s_gx1[tid] = x1; s_gy1[tid] = y1;
        s_ga[tid]  = ga;
    }
    __syncthreads();
    const int p = 2 * (blockIdx.x * 256 + tid);
    if (p >= NP) return;
    const float4 pb0 = reinterpret_cast<const float4*>(pred)[(size_t)b * NP + p];
    const float4 pb1 = reinterpret_cast<const float4*>(pred)[(size_t)b * NP + p + 1];
    float hw0 = 0.5f * pb0.z, hh0 = 0.5f * pb0.w;
    const float ax0 = pb0.x - hw0, ay0 = pb0.y - hh0;
    const float ax1 = pb0.x + hw0, ay1 = pb0.y + hh0;
    float pa0 = (ax1 - ax0) * (ay1 - ay0); opaque(pa0);
    float hw1 = 0.5f * pb1.z, hh1 = 0.5f * pb1.w;
    const float bx0 = pb1.x - hw1, by0 = pb1.y - hh1;
    const float bx1 = pb1.x + hw1, by1 = pb1.y + hh1;
    float pa1 = (bx1 - bx0) * (by1 - by0); opaque(pa1);
    float maxv0 = 0.0f, maxv1 = 0.0f;
    const size_t base = (size_t)b * NG * NP + (size_t)p;
    #pragma unroll 8
    for (int g = 0; g < NG; ++g) {
        const float gx0 = s_gx0[g], gy0 = s_gy0[g];
        const float gx1 = s_gx1[g], gy1 = s_gy1[g];
        const float ga  = s_ga[g];
        float w0 = fmaxf(fminf(gx1, ax1) - fmaxf(gx0, ax0), 0.0f);
        float h0 = fmaxf(fminf(gy1, ay1) - fmaxf(gy0, ay0), 0.0f);
        float inter0 = w0 * h0; opaque(inter0);
        float iou0 = inter0 / ((ga + pa0) - inter0);
        float w1 = fmaxf(fminf(gx1, bx1) - fmaxf(gx0, bx0), 0.0f);
        float h1 = fmaxf(fminf(gy1, by1) - fmaxf(gy0, by0), 0.0f);
        float inter1 = w1 * h1; opaque(inter1);
        float iou1 = inter1 / ((ga + pa1) - inter1);
        float2 vi; vi.x = iou0; vi.y = iou1;
        *reinterpret_cast<float2*>(out_iou + base + (size_t)g * NP) = vi;
        float2 vp; vp.x = (iou0 > 0.7f) ? 1.0f : 0.0f;
                   vp.y = (iou1 > 0.7f) ? 1.0f : 0.0f;
        *reinterpret_cast<float2*>(out_pos + base + (size_t)g * NP) = vp;
        maxv0 = fmaxf(maxv0, iou0);
        maxv1 = fmaxf(maxv1, iou1);
    }
    float2 vn; vn.x = (maxv0 < 0.3f) ? 1.0f : 0.0f;
               vn.y = (maxv1 < 0.3f) ? 1.0f : 0.0f;
    *reinterpret_cast<float2*>(out_neg + (size_t)b * NP + p) = vn;
}

__global__ __launch_bounds__(256) void argmax_scan(
    const float* __restrict__ out_iou,
    float* __restrict__ out_pos)
{
    const int row = blockIdx.x;
    const float4* r4 = reinterpret_cast<const float4*>(out_iou + (size_t)row * NP);
    float bv = -1.0f;
    int   bi = 0x7fffffff;
    for (int c = threadIdx.x; c < NP / 4; c += 256) {
        float4 v = r4[c];
        int p = 4 * c;
        if (v.x > bv) { bv = v.x; bi = p; }
        if (v.y > bv) { bv = v.y; bi = p + 1; }
        if (v.z > bv) { bv = v.z; bi = p + 2; }
        if (v.w > bv) { bv = v.w; bi = p + 3; }
    }
    #pragma unroll
    for (int s = 1; s < 64; s <<= 1) {
        float ov = __shfl_xor(bv, s, 64);
        int   oi = __shfl_xor(bi, s, 64);
        if (ov > bv || (ov == bv && oi < bi)) { bv = ov; bi = oi; }
    }
    __shared__ float sv[4];
    __shared__ int   si[4];
    const int wid = threadIdx.x >> 6;
    if ((threadIdx.x & 63) == 0) { sv[wid] = bv; si[wid] = bi; }
    __syncthreads();
    if (threadIdx.x == 0) {
        for (int w = 1; w < 4; ++w)
            if (sv[w] > bv || (sv[w] == bv && si[w] < bi)) { bv = sv[w]; bi = si[w]; }
        out_pos[(size_t)row * NP + bi] = 1.0f;
    }
}

extern "C" void kernel_launch(void* const* d_in, const int* in_sizes, int n_in,
                              void* d_out, int out_size, void* d_ws, size_t ws_size,
                              hipStream_t stream) {
    const float* pred = (const float*)d_in[0];
    const float* gt   = (const float*)d_in[1];
    float* out_iou = (float*)d_out;
    float* out_pos = out_iou + (size_t)NB * NG * NP;
    float* out_neg = out_pos + (size_t)NB * NG * NP;

    const size_t part_bytes = (size_t)NB * NG * NCH * sizeof(unsigned long long);  // 102 KB
    const size_t neg_bytes  = (size_t)NB * NGG * NP * sizeof(float);               // 12.8 MB

    if (ws_size >= part_bytes + neg_bytes) {
        unsigned long long* part = (unsigned long long*)d_ws;
        float* negpart = (float*)((char*)d_ws + part_bytes);
        unified<<<dim3(NCH, NGG, NB), dim3(256), 0, stream>>>(
            pred, gt, out_iou, out_pos, negpart, part);
        fix_combined<<<dim3(NNEG4 + 2), dim3(256), 0, stream>>>(part, negpart, out_pos, out_neg);
    } else {
        stream2_full<<<dim3(98, NB), dim3(256), 0, stream>>>(pred, gt, out_iou, out_pos, out_neg);
        argmax_scan<<<dim3(NB * NG), dim3(256), 0, stream>>>(out_iou, out_pos);
    }
}

// Round 19
// 50.513 us; speedup vs baseline: 1.2904x; 1.0437x over previous
//
#include <hip/hip_runtime.h>
#include <cstdint>
#include <cstddef>

#define NB 8
#define NG 64
#define NP 50000
#define CH 2000                  // preds per chunk (25*2000 = NP exactly)
#define NCH 25                   // p-chunks
#define NGG 8                    // g-groups of 8
#define NNEG4 ((NB * NP / 4 + 255) / 256)  // 391 neg-combine blocks (float4 out)

__device__ __forceinline__ void opaque(float& x) { asm volatile("" : "+v"(x)); }
__device__ __forceinline__ unsigned long long umax64(unsigned long long a, unsigned long long b) {
    return a > b ? a : b;
}

// ---------------------------------------------------------------------------
// UNIFIED row-oriented kernel (R18-proven, 52.7 µs): computes each iou exactly
// once. One change: negpart is now a 1-BYTE flag per (gg,p) — "group-max <
// 0.3" — instead of the f32 partial max. (max<T) == AND of (iou<T), exact.
// Slab: 12.8 MB -> 3.2 MB; combine pass reads 4x less.
__global__ __launch_bounds__(256) void unified(
    const float* __restrict__ pred,
    const float* __restrict__ gt,
    float* __restrict__ out_iou,
    float* __restrict__ out_pos,
    unsigned char* __restrict__ negpart,
    unsigned long long* __restrict__ part)
{
    __shared__ float s_gx0[8], s_gy0[8], s_gx1[8], s_gy1[8], s_ga[8];
    const int b  = blockIdx.z;
    const int gg = blockIdx.y;
    const int p0 = blockIdx.x * CH;
    const int tid = threadIdx.x;

    if (tid < 8) {
        const float4 gb = reinterpret_cast<const float4*>(gt)[b * NG + gg * 8 + tid];
        float hw = 0.5f * gb.z, hh = 0.5f * gb.w;   // exact, FMA-safe
        float x0 = gb.x - hw, y0 = gb.y - hh;
        float x1 = gb.x + hw, y1 = gb.y + hh;
        float ga = (x1 - x0) * (y1 - y0);
        opaque(ga);
        s_gx0[tid] = x0; s_gy0[tid] = y0;
        s_gx1[tid] = x1; s_gy1[tid] = y1;
        s_ga[tid]  = ga;
    }
    __syncthreads();

    float        bv[8] = {-1.f,-1.f,-1.f,-1.f,-1.f,-1.f,-1.f,-1.f};
    unsigned int bp[8] = {0,0,0,0,0,0,0,0};

    #pragma unroll 1
    for (int idx = tid; idx < CH / 2; idx += 256) {   // 1000 pred-pairs
        const int p = p0 + 2 * idx;
        const float4 pb0 = reinterpret_cast<const float4*>(pred)[(size_t)b * NP + p];
        const float4 pb1 = reinterpret_cast<const float4*>(pred)[(size_t)b * NP + p + 1];

        float hw0 = 0.5f * pb0.z, hh0 = 0.5f * pb0.w;
        const float ax0 = pb0.x - hw0, ay0 = pb0.y - hh0;
        const float ax1 = pb0.x + hw0, ay1 = pb0.y + hh0;
        float pa0 = (ax1 - ax0) * (ay1 - ay0);
        opaque(pa0);

        float hw1 = 0.5f * pb1.z, hh1 = 0.5f * pb1.w;
        const float bx0 = pb1.x - hw1, by0 = pb1.y - hh1;
        const float bx1 = pb1.x + hw1, by1 = pb1.y + hh1;
        float pa1 = (bx1 - bx0) * (by1 - by0);
        opaque(pa1);

        float cmax0 = 0.0f, cmax1 = 0.0f;
        const size_t rbase = (size_t)b * NG * NP + (size_t)(gg * 8) * NP + (size_t)p;

        #pragma unroll
        for (int j = 0; j < 8; ++j) {
            const float gx0 = s_gx0[j], gy0 = s_gy0[j];
            const float gx1 = s_gx1[j], gy1 = s_gy1[j];
            const float ga  = s_ga[j];

            float w0 = fmaxf(fminf(gx1, ax1) - fmaxf(gx0, ax0), 0.0f);
            float h0 = fmaxf(fminf(gy1, ay1) - fmaxf(gy0, ay0), 0.0f);
            float inter0 = w0 * h0;
            opaque(inter0);                          // numpy op order: (ga+pa)-inter
            float iou0 = inter0 / ((ga + pa0) - inter0);  // IEEE div

            float w1 = fmaxf(fminf(gx1, bx1) - fmaxf(gx0, bx0), 0.0f);
            float h1 = fmaxf(fminf(gy1, by1) - fmaxf(gy0, by0), 0.0f);
            float inter1 = w1 * h1;
            opaque(inter1);
            float iou1 = inter1 / ((ga + pa1) - inter1);

            float2 vi; vi.x = iou0; vi.y = iou1;
            *reinterpret_cast<float2*>(out_iou + rbase + (size_t)j * NP) = vi;

            float2 vp; vp.x = (iou0 > 0.7f) ? 1.0f : 0.0f;
                       vp.y = (iou1 > 0.7f) ? 1.0f : 0.0f;
            *reinterpret_cast<float2*>(out_pos + rbase + (size_t)j * NP) = vp;

            cmax0 = fmaxf(cmax0, iou0);
            cmax1 = fmaxf(cmax1, iou1);

            // argmax accumulate: strict >, ascending p -> first occurrence
            if (iou0 > bv[j]) { bv[j] = iou0; bp[j] = (unsigned int)p; }
            if (iou1 > bv[j]) { bv[j] = iou1; bp[j] = (unsigned int)(p + 1); }
        }

        uchar2 fl;                                   // 1 iff all 8 ious < 0.3 (== group-max < 0.3)
        fl.x = (cmax0 < 0.3f) ? 1 : 0;
        fl.y = (cmax1 < 0.3f) ? 1 : 0;
        *reinterpret_cast<uchar2*>(negpart + ((size_t)b * NGG + gg) * NP + p) = fl;
    }

    // per-block argmax reduction: butterfly within wave, LDS across 4 waves
    __shared__ unsigned long long s_part[8][4];
    const int lane = tid & 63;
    const int wv = tid >> 6;
    #pragma unroll
    for (int j = 0; j < 8; ++j) {
        unsigned long long k = 0;
        if (bv[j] >= 0.0f)
            k = ((unsigned long long)__float_as_uint(bv[j]) << 32) |
                (unsigned long long)(0xFFFFFFFFu - bp[j]);
        #pragma unroll
        for (int s = 1; s < 64; s <<= 1)
            k = umax64(k, __shfl_xor(k, s, 64));
        if (lane == 0) s_part[j][wv] = k;
    }
    __syncthreads();

    if (tid < 8) {
        unsigned long long r = umax64(umax64(s_part[tid][0], s_part[tid][1]),
                                      umax64(s_part[tid][2], s_part[tid][3]));
        part[((size_t)b * NG + (size_t)(gg * 8 + tid)) * NCH + blockIdx.x] = r;
    }
}

// Combined fixup: blocks [0,NNEG4) AND 8 flag slabs -> neg; last 2 blocks
// reduce 25 partial keys per row and set the argmax bit in pos.
__global__ __launch_bounds__(256) void fix_combined(
    const unsigned long long* __restrict__ part,
    const unsigned char* __restrict__ negpart,
    float* __restrict__ out_pos,
    float* __restrict__ out_neg)
{
    const int bid = blockIdx.x;
    const int tid = threadIdx.x;

    if (bid < NNEG4) {
        const int idx = bid * 256 + tid;             // float4 index over NB*NP/4
        if (idx < NB * (NP / 4)) {
            const int b = idx / (NP / 4);
            const int p = 4 * (idx % (NP / 4));
            uchar4 m = *reinterpret_cast<const uchar4*>(negpart + ((size_t)b * NGG + 0) * NP + p);
            #pragma unroll
            for (int gg = 1; gg < NGG; ++gg) {
                const uchar4 t = *reinterpret_cast<const uchar4*>(negpart + ((size_t)b * NGG + gg) * NP + p);
                m.x &= t.x; m.y &= t.y; m.z &= t.z; m.w &= t.w;
            }
            float4 vn;
            vn.x = m.x ? 1.0f : 0.0f;
            vn.y = m.y ? 1.0f : 0.0f;
            vn.z = m.z ? 1.0f : 0.0f;
            vn.w = m.w ? 1.0f : 0.0f;
            *reinterpret_cast<float4*>(out_neg + (size_t)b * NP + p) = vn;
        }
    } else {
        const int row = (bid - NNEG4) * 256 + tid;   // b*NG + g
        if (row < NB * NG) {
            const unsigned long long* pr = part + (size_t)row * NCH;
            unsigned long long r = pr[0];
            #pragma unroll
            for (int c = 1; c < NCH; ++c) r = umax64(r, pr[c]);
            unsigned int idx = 0xFFFFFFFFu - (unsigned int)(r & 0xFFFFFFFFull);
            if (idx < NP) out_pos[(size_t)row * NP + idx] = 1.0f;
        }
    }
}

// ------------------- fallback path (ws too small): R3-proven -------------------
__global__ __launch_bounds__(256) void stream2_full(
    const float* __restrict__ pred,
    const float* __restrict__ gt,
    float* __restrict__ out_iou,
    float* __restrict__ out_pos,
    float* __restrict__ out_neg)
{
    __shared__ float s_gx0[NG], s_gy0[NG], s_gx1[NG], s_gy1[NG], s_ga[NG];
    const int b = blockIdx.y;
    const int tid = threadIdx.x;
    if (tid < NG) {
        const float4 gb = reinterpret_cast<const float4*>(gt)[b * NG + tid];
        float hw = 0.5f * gb.z, hh = 0.5f * gb.w;
        float x0 = gb.x - hw, y0 = gb.y - hh;
        float x1 = gb.x + hw, y1 = gb.y + hh;
        float ga = (x1 - x0) * (y1 - y0);
        opaque(ga);
        s_gx0[tid] = x0; s_gy0[tid] = y0;
        s_gx1[tid] = x1; s_gy1[tid] = y1;
        s_ga[tid]  = ga;
    }
    __syncthreads();
    const int p = 2 * (blockIdx.x * 256 + tid);
    if (p >= NP) return;
    const float4 pb0 = reinterpret_cast<const float4*>(pred)[(size_t)b * NP + p];
    const float4 pb1 = reinterpret_cast<const float4*>(pred)[(size_t)b * NP + p + 1];
    float hw0 = 0.5f * pb0.z, hh0 = 0.5f * pb0.w;
    const float ax0 = pb0.x - hw0, ay0 = pb0.y - hh0;
    const float ax1 = pb0.x + hw0, ay1 = pb0.y + hh0;
    float pa0 = (ax1 - ax0) * (ay1 - ay0); opaque(pa0);
    float hw1 = 0.5f * pb1.z, hh1 = 0.5f * pb1.w;
    const float bx0 = pb1.x - hw1, by0 = pb1.y - hh1;
    const float bx1 = pb1.x + hw1, by1 = pb1.y + hh1;
    float pa1 = (bx1 - bx0) * (by1 - by0); opaque(pa1);
    float maxv0 = 0.0f, maxv1 = 0.0f;
    const size_t base = (size_t)b * NG * NP + (size_t)p;
    #pragma unroll 8
    for (int g = 0; g < NG; ++g) {
        const float gx0 = s_gx0[g], gy0 = s_gy0[g];
        const float gx1 = s_gx1[g], gy1 = s_gy1[g];
        const float ga  = s_ga[g];
        float w0 = fmaxf(fminf(gx1, ax1) - fmaxf(gx0, ax0), 0.0f);
        float h0 = fmaxf(fminf(gy1, ay1) - fmaxf(gy0, ay0), 0.0f);
        float inter0 = w0 * h0; opaque(inter0);
        float iou0 = inter0 / ((ga + pa0) - inter0);
        float w1 = fmaxf(fminf(gx1, bx1) - fmaxf(gx0, bx0), 0.0f);
        float h1 = fmaxf(fminf(gy1, by1) - fmaxf(gy0, by0), 0.0f);
        float inter1 = w1 * h1; opaque(inter1);
        float iou1 = inter1 / ((ga + pa1) - inter1);
        float2 vi; vi.x = iou0; vi.y = iou1;
        *reinterpret_cast<float2*>(out_iou + base + (size_t)g * NP) = vi;
        float2 vp; vp.x = (iou0 > 0.7f) ? 1.0f : 0.0f;
                   vp.y = (iou1 > 0.7f) ? 1.0f : 0.0f;
        *reinterpret_cast<float2*>(out_pos + base + (size_t)g * NP) = vp;
        maxv0 = fmaxf(maxv0, iou0);
        maxv1 = fmaxf(maxv1, iou1);
    }
    float2 vn; vn.x = (maxv0 < 0.3f) ? 1.0f : 0.0f;
               vn.y = (maxv1 < 0.3f) ? 1.0f : 0.0f;
    *reinterpret_cast<float2*>(out_neg + (size_t)b * NP + p) = vn;
}

__global__ __launch_bounds__(256) void argmax_scan(
    const float* __restrict__ out_iou,
    float* __restrict__ out_pos)
{
    const int row = blockIdx.x;
    const float4* r4 = reinterpret_cast<const float4*>(out_iou + (size_t)row * NP);
    float bv = -1.0f;
    int   bi = 0x7fffffff;
    for (int c = threadIdx.x; c < NP / 4; c += 256) {
        float4 v = r4[c];
        int p = 4 * c;
        if (v.x > bv) { bv = v.x; bi = p; }
        if (v.y > bv) { bv = v.y; bi = p + 1; }
        if (v.z > bv) { bv = v.z; bi = p + 2; }
        if (v.w > bv) { bv = v.w; bi = p + 3; }
    }
    #pragma unroll
    for (int s = 1; s < 64; s <<= 1) {
        float ov = __shfl_xor(bv, s, 64);
        int   oi = __shfl_xor(bi, s, 64);
        if (ov > bv || (ov == bv && oi < bi)) { bv = ov; bi = oi; }
    }
    __shared__ float sv[4];
    __shared__ int   si[4];
    const int wid = threadIdx.x >> 6;
    if ((threadIdx.x & 63) == 0) { sv[wid] = bv; si[wid] = bi; }
    __syncthreads();
    if (threadIdx.x == 0) {
        for (int w = 1; w < 4; ++w)
            if (sv[w] > bv || (sv[w] == bv && si[w] < bi)) { bv = sv[w]; bi = si[w]; }
        out_pos[(size_t)row * NP + bi] = 1.0f;
    }
}

extern "C" void kernel_launch(void* const* d_in, const int* in_sizes, int n_in,
                              void* d_out, int out_size, void* d_ws, size_t ws_size,
                              hipStream_t stream) {
    const float* pred = (const float*)d_in[0];
    const float* gt   = (const float*)d_in[1];
    float* out_iou = (float*)d_out;
    float* out_pos = out_iou + (size_t)NB * NG * NP;
    float* out_neg = out_pos + (size_t)NB * NG * NP;

    const size_t part_bytes = (size_t)NB * NG * NCH * sizeof(unsigned long long);  // 102 KB
    const size_t neg_bytes  = (size_t)NB * NGG * NP;                               // 3.2 MB (u8)

    if (ws_size >= part_bytes + neg_bytes) {
        unsigned long long* part = (unsigned long long*)d_ws;
        unsigned char* negpart = (unsigned char*)d_ws + part_bytes;
        unified<<<dim3(NCH, NGG, NB), dim3(256), 0, stream>>>(
            pred, gt, out_iou, out_pos, negpart, part);
        fix_combined<<<dim3(NNEG4 + 2), dim3(256), 0, stream>>>(part, negpart, out_pos, out_neg);
    } else {
        stream2_full<<<dim3(98, NB), dim3(256), 0, stream>>>(pred, gt, out_iou, out_pos, out_neg);
        argmax_scan<<<dim3(NB * NG), dim3(256), 0, stream>>>(out_iou, out_pos);
    }
}